// Round 9
// baseline (132.213 us; speedup 1.0000x reference)
//
#include <hip/hip_runtime.h>

#define NPIX (128 * 128)
#define CH 64
#define RMID 16
#define KK 9
#define TOTPIX (8 * NPIX)        // 131072

typedef float v2f __attribute__((ext_vector_type(2)));

// ---------------- K1: conv1 + PReLU -> t_ws ----------------
// 2 threads per pixel, channel-split 32+32, LDS combine. Memory/latency
// shaped (VALU issue ~1.7 us total) — left scalar. No min-waves bound:
// capping VGPRs spills xv[32]+t[16] to scratch (round 7: 111 MB WRITE).
__global__ __launch_bounds__(256) void conv1_kernel(
    const float* __restrict__ x,
    const float* __restrict__ w1,
    const float* __restrict__ b1,
    const float* __restrict__ prelu_a,
    float* __restrict__ t_ws)
{
    __shared__ float pl[2][128][17];     // [layer][px][r], stride 17

    const int px    = threadIdx.x & 127;
    const int layer = threadIdx.x >> 7;  // wave-pair uniform

    const int G  = blockIdx.x * 128 + px;    // pixel id 0..131071
    const int bq = G >> 14;
    const int p  = G & (NPIX - 1);

    const float* xp = x + (size_t)bq * CH * NPIX + (size_t)(32 * layer) * NPIX + p;

    float xv[32];
#pragma unroll
    for (int c = 0; c < 32; ++c) xv[c] = xp[(size_t)c * NPIX];   // all loads in flight

    float t[RMID];
#pragma unroll
    for (int r = 0; r < RMID; ++r) t[r] = (layer == 0) ? b1[r] : 0.f;

#pragma unroll
    for (int c = 0; c < 32; ++c) {
#pragma unroll
        for (int r = 0; r < RMID; ++r)
            t[r] = fmaf(w1[r * CH + 32 * layer + c], xv[c], t[r]);  // uniform -> s_load
    }
#pragma unroll
    for (int r = 0; r < RMID; ++r) pl[layer][px][r] = t[r];
    __syncthreads();

    const float a  = prelu_a[0];
    const int   r0 = 8 * layer;
#pragma unroll
    for (int r = 0; r < 8; ++r) {
        const float v = pl[0][px][r0 + r] + pl[1][px][r0 + r];
        t_ws[(r0 + r) * TOTPIX + G] = (v >= 0.f) ? v : a * v;
    }
}

// ---------------- K2: conv2 (weight gen) + involution ----------------
// Round-6/8 structure (XCD-pinned: bq=L&7, gq=(L>>3)&7 fastest, strip=L>>6;
// FETCH clean at 38 MB) with the hot math in float2 so the compiler emits
// v_pk_fma_f32 (VOP3P, 2 FMA/instr — the only path to the 157 TF fp32 rate):
//   conv2 gen: 144 fma -> 72 pk + 9 hadd ; combine: 18 fma -> 9 pk.
// w2 r-pairs are contiguous+uniform (64-bit SGPR operand); tr held as v2f[8].
__global__ __launch_bounds__(256) void invol_kernel(
    const float* __restrict__ x,
    const float* __restrict__ t_ws,
    const float* __restrict__ w2,
    const float* __restrict__ b2,
    float* __restrict__ out)
{
    const int px   = threadIdx.x & 127;
    const int rsub = threadIdx.x >> 7;          // 0..1

    const int L     = blockIdx.x;               // 0..4095
    const int bq    = L & 7;                    // batch == XCD pin
    const int gq    = (L >> 3) & 7;             // group-quad (fastest per XCD)
    const int strip = L >> 6;                   // 0..63 row-pair

    const int hq = 2 * strip + rsub;
    const int p  = hq * 128 + px;

    // t fragment as v2f pairs (r-major pairs match w2's contiguous layout)
    const int G = (bq << 14) + p;
    v2f tr2[RMID / 2];
#pragma unroll
    for (int r = 0; r < RMID / 2; ++r) {
        v2f v;
        v.x = t_ws[(2 * r)     * TOTPIX + G];
        v.y = t_ws[(2 * r + 1) * TOTPIX + G];
        tr2[r] = v;
    }

    // per-lane clamped column byte-offsets + masks
    const int   pb   = 4 * p;
    const int   cneg = (px > 0)   ? pb - 4 : pb;
    const int   cpos = (px < 127) ? pb + 4 : pb;
    const float mneg = (px > 0)   ? 1.f : 0.f;
    const float mpos = (px < 127) ? 1.f : 0.f;

    // row offsets (wave-uniform)
    const int   ro0 = (hq > 0)   ? -512 : 0;
    const int   ro2 = (hq < 127) ?  512 : 0;
    const float rm0 = (hq > 0)   ? 1.f : 0.f;
    const float rm2 = (hq < 127) ? 1.f : 0.f;

    const char* xbc = (const char*)(x   + (size_t)bq * CH * NPIX);
    char*       obc = (char*)      (out + (size_t)bq * CH * NPIX);

#pragma unroll 2
    for (int gi = 0; gi < 4; ++gi) {
        const int g = 4 * gq + gi;                        // block-uniform
        const char* c0 = xbc + (size_t)(2 * g) * NPIX * 4;
        const char* c1 = c0 + NPIX * 4;

        // -- 18 stencil loads, batched --
        float p0[KK], p1[KK];
#pragma unroll
        for (int i = 0; i < 3; ++i) {
            const int ro = (i == 0) ? ro0 : (i == 2) ? ro2 : 0;
#pragma unroll
            for (int j = 0; j < 3; ++j) {
                const int k    = i * 3 + j;
                const int voff = (j == 0) ? cneg : (j == 2) ? cpos : pb;
                p0[k] = *(const float*)(c0 + (size_t)(voff + ro));
                p1[k] = *(const float*)(c1 + (size_t)(voff + ro));
            }
        }

        // -- conv2: 9 weights, packed reduction over r-pairs --
        float wg[KK];
#pragma unroll
        for (int k = 0; k < KK; ++k) {
            const v2f* w2r2 = (const v2f*)(w2 + (g * KK + k) * RMID);  // 64B-aligned, uniform
            v2f acc2;
            acc2.x = b2[g * KK + k];
            acc2.y = 0.f;
#pragma unroll
            for (int r = 0; r < RMID / 2; ++r)
                acc2 = __builtin_elementwise_fma(w2r2[r], tr2[r], acc2);  // v_pk_fma_f32
            wg[k] = acc2.x + acc2.y;
        }
        // fold border masks
        wg[0] *= mneg * rm0;  wg[1] *= rm0;  wg[2] *= mpos * rm0;
        wg[3] *= mneg;                       wg[5] *= mpos;
        wg[6] *= mneg * rm2;  wg[7] *= rm2;  wg[8] *= mpos * rm2;

        // -- combine (o0,o1) packed + nontemporal store --
        v2f o; o.x = 0.f; o.y = 0.f;
#pragma unroll
        for (int k = 0; k < KK; ++k) {
            v2f wk; wk.x = wg[k]; wk.y = wg[k];           // splat (op_sel broadcast)
            v2f pk; pk.x = p0[k]; pk.y = p1[k];
            o = __builtin_elementwise_fma(wk, pk, o);      // v_pk_fma_f32
        }
        __builtin_nontemporal_store(o.x, (float*)(obc + (size_t)(2 * g)     * NPIX * 4 + pb));
        __builtin_nontemporal_store(o.y, (float*)(obc + (size_t)(2 * g + 1) * NPIX * 4 + pb));
    }
}

extern "C" void kernel_launch(void* const* d_in, const int* in_sizes, int n_in,
                              void* d_out, int out_size, void* d_ws, size_t ws_size,
                              hipStream_t stream)
{
    const float* x  = (const float*)d_in[0];
    const float* w1 = (const float*)d_in[1];
    const float* b1 = (const float*)d_in[2];
    const float* pa = (const float*)d_in[3];
    const float* w2 = (const float*)d_in[4];
    const float* b2 = (const float*)d_in[5];
    float* out  = (float*)d_out;
    float* t_ws = (float*)d_ws;              // 16 * 131072 * 4 B = 8.4 MB

    hipLaunchKernelGGL(conv1_kernel, dim3(TOTPIX / 128), dim3(256), 0, stream,
                       x, w1, b1, pa, t_ws);
    hipLaunchKernelGGL(invol_kernel, dim3(8 * 8 * 64), dim3(256), 0, stream,
                       x, t_ws, w2, b2, out);
}

// Round 10
// 128.661 us; speedup vs baseline: 1.0276x; 1.0276x over previous
//
#include <hip/hip_runtime.h>

#define NPIX (128 * 128)
#define CH 64
#define RMID 16
#define KK 9
#define TOTPIX (8 * NPIX)        // 131072
#define PLANE_B 65536            // bytes per channel plane

typedef float v2f __attribute__((ext_vector_type(2)));

// ---------------- K1: conv1 + PReLU -> t_ws ---------------- (unchanged r8/r9)
__global__ __launch_bounds__(256) void conv1_kernel(
    const float* __restrict__ x,
    const float* __restrict__ w1,
    const float* __restrict__ b1,
    const float* __restrict__ prelu_a,
    float* __restrict__ t_ws)
{
    __shared__ float pl[2][128][17];

    const int px    = threadIdx.x & 127;
    const int layer = threadIdx.x >> 7;

    const int G  = blockIdx.x * 128 + px;
    const int bq = G >> 14;
    const int p  = G & (NPIX - 1);

    const float* xp = x + (size_t)bq * CH * NPIX + (size_t)(32 * layer) * NPIX + p;

    float xv[32];
#pragma unroll
    for (int c = 0; c < 32; ++c) xv[c] = xp[(size_t)c * NPIX];

    float t[RMID];
#pragma unroll
    for (int r = 0; r < RMID; ++r) t[r] = (layer == 0) ? b1[r] : 0.f;

#pragma unroll
    for (int c = 0; c < 32; ++c) {
#pragma unroll
        for (int r = 0; r < RMID; ++r)
            t[r] = fmaf(w1[r * CH + 32 * layer + c], xv[c], t[r]);
    }
#pragma unroll
    for (int r = 0; r < RMID; ++r) pl[layer][px][r] = t[r];
    __syncthreads();

    const float a  = prelu_a[0];
    const int   r0 = 8 * layer;
#pragma unroll
    for (int r = 0; r < 8; ++r) {
        const float v = pl[0][px][r0 + r] + pl[1][px][r0 + r];
        t_ws[(r0 + r) * TOTPIX + G] = (v >= 0.f) ? v : a * v;
    }
}

// ---------------- K2: conv2 (weight gen) + involution ----------------
// Pixel-pair threads: wave = one image row (64 lanes x 2 px). Per plane a
// thread loads only its own 2 columns x 3 rows (dwordx2); the +-1 column
// taps come from lane shuffles (wave spans the full row -> missing neighbor
// data only at image borders, which are zero-masked anyway).
// vmem instrs/px: 96 -> 23. XCD-pinned grid: bq=L&7, gq=(L>>3)&7, strip=L>>6.
__global__ __launch_bounds__(256) void invol_kernel(
    const float* __restrict__ x,
    const float* __restrict__ t_ws,
    const float* __restrict__ w2,
    const float* __restrict__ b2,
    float* __restrict__ out)
{
    const int c    = threadIdx.x & 63;    // column-pair id (cols 2c, 2c+1)
    const int rsub = threadIdx.x >> 6;    // 0..3: row within strip; wave-uniform

    const int L     = blockIdx.x;         // 0..2047
    const int bq    = L & 7;              // batch == XCD pin
    const int gq    = (L >> 3) & 7;       // group-quad (consecutive on one XCD)
    const int strip = L >> 6;             // 0..31 (4 rows each)

    const int hq   = 4 * strip + rsub;
    const int col0 = 2 * c;
    const int p0   = hq * 128 + col0;

    // ---- t for both pixels, transposed to px-major r-pairs ----
    const int G0 = (bq << 14) + p0;
    v2f trA[8], trB[8];                   // trA[i] = (t_{2i}(px0), t_{2i+1}(px0))
#pragma unroll
    for (int i = 0; i < 8; ++i) {
        const v2f va = *(const v2f*)(t_ws + (size_t)(2 * i)     * TOTPIX + G0);
        const v2f vb = *(const v2f*)(t_ws + (size_t)(2 * i + 1) * TOTPIX + G0);
        trA[i].x = va.x; trA[i].y = vb.x;
        trB[i].x = va.y; trB[i].y = vb.y;
    }

    // ---- masks (border zero-padding) ----
    const float rm0 = (hq > 0)   ? 1.f : 0.f;     // wave-uniform
    const float rm2 = (hq < 127) ? 1.f : 0.f;
    const float mL  = (c > 0)    ? 1.f : 0.f;     // px0 left tap (col 2c-1)
    const float mR  = (c < 63)   ? 1.f : 0.f;     // px1 right tap (col 2c+2)
    v2f mk[KK];
#pragma unroll
    for (int i = 0; i < 3; ++i) {
        const float rmv = (i == 0) ? rm0 : (i == 2) ? rm2 : 1.f;
        mk[i * 3 + 0].x = rmv * mL;  mk[i * 3 + 0].y = rmv;
        mk[i * 3 + 1].x = rmv;       mk[i * 3 + 1].y = rmv;
        mk[i * 3 + 2].x = rmv;       mk[i * 3 + 2].y = rmv * mR;
    }

    // row byte-offsets (clamped; masked rows read row hq instead)
    const int ro0 = (hq > 0)   ? -512 : 0;
    const int ro2 = (hq < 127) ?  512 : 0;

    const char* xbc = (const char*)(x   + (size_t)bq * CH * NPIX);
    char*       obc = (char*)      (out + (size_t)bq * CH * NPIX);
    const int   pb0 = 4 * p0;

#pragma unroll
    for (int gi = 0; gi < 4; ++gi) {
        const int g = 4 * gq + gi;                        // block-uniform
        const char* c0p = xbc + (size_t)(2 * g) * PLANE_B;
        const char* c1p = c0p + PLANE_B;

        // -- own-column loads: 3 rows x 2 planes, dwordx2 --
        const v2f a0 = *(const v2f*)(c0p + (size_t)(pb0 + ro0));
        const v2f a1 = *(const v2f*)(c0p + (size_t)pb0);
        const v2f a2 = *(const v2f*)(c0p + (size_t)(pb0 + ro2));
        const v2f e0 = *(const v2f*)(c1p + (size_t)(pb0 + ro0));
        const v2f e1 = *(const v2f*)(c1p + (size_t)pb0);
        const v2f e2 = *(const v2f*)(c1p + (size_t)(pb0 + ro2));

        // -- weight gen: pk over r-pairs, per pixel (covers load/shfl latency) --
        v2f wgp[KK];                                      // (wg(px0), wg(px1)) masked
#pragma unroll
        for (int k = 0; k < KK; ++k) {
            const v2f* w2r2 = (const v2f*)(w2 + (g * KK + k) * RMID);  // uniform sgpr-pairs
            v2f accA, accB;
            accA.x = b2[g * KK + k]; accA.y = 0.f;
            accB = accA;
#pragma unroll
            for (int r = 0; r < RMID / 2; ++r) {
                accA = __builtin_elementwise_fma(w2r2[r], trA[r], accA);
                accB = __builtin_elementwise_fma(w2r2[r], trB[r], accB);
            }
            v2f wk;
            wk.x = accA.x + accA.y;
            wk.y = accB.x + accB.y;
            wgp[k] = wk * mk[k];
        }

        // -- neighbor columns via lane shuffle (wave = full row) --
        const float lA0 = __shfl_up(a0.y, 1), rA0 = __shfl_down(a0.x, 1);
        const float lA1 = __shfl_up(a1.y, 1), rA1 = __shfl_down(a1.x, 1);
        const float lA2 = __shfl_up(a2.y, 1), rA2 = __shfl_down(a2.x, 1);
        const float lE0 = __shfl_up(e0.y, 1), rE0 = __shfl_down(e0.x, 1);
        const float lE1 = __shfl_up(e1.y, 1), rE1 = __shfl_down(e1.x, 1);
        const float lE2 = __shfl_up(e2.y, 1), rE2 = __shfl_down(e2.x, 1);

        // -- combine: o = sum_k wgp[k] * (tap(px0), tap(px1)) --
        v2f oA; oA.x = 0.f; oA.y = 0.f;
        v2f oB = oA;
        {
            v2f tp;
            tp.x = lA0;  tp.y = a0.x;  oA = __builtin_elementwise_fma(wgp[0], tp, oA);
                                        oA = __builtin_elementwise_fma(wgp[1], a0, oA);
            tp.x = a0.y; tp.y = rA0;   oA = __builtin_elementwise_fma(wgp[2], tp, oA);
            tp.x = lA1;  tp.y = a1.x;  oA = __builtin_elementwise_fma(wgp[3], tp, oA);
                                        oA = __builtin_elementwise_fma(wgp[4], a1, oA);
            tp.x = a1.y; tp.y = rA1;   oA = __builtin_elementwise_fma(wgp[5], tp, oA);
            tp.x = lA2;  tp.y = a2.x;  oA = __builtin_elementwise_fma(wgp[6], tp, oA);
                                        oA = __builtin_elementwise_fma(wgp[7], a2, oA);
            tp.x = a2.y; tp.y = rA2;   oA = __builtin_elementwise_fma(wgp[8], tp, oA);

            tp.x = lE0;  tp.y = e0.x;  oB = __builtin_elementwise_fma(wgp[0], tp, oB);
                                        oB = __builtin_elementwise_fma(wgp[1], e0, oB);
            tp.x = e0.y; tp.y = rE0;   oB = __builtin_elementwise_fma(wgp[2], tp, oB);
            tp.x = lE1;  tp.y = e1.x;  oB = __builtin_elementwise_fma(wgp[3], tp, oB);
                                        oB = __builtin_elementwise_fma(wgp[4], e1, oB);
            tp.x = e1.y; tp.y = rE1;   oB = __builtin_elementwise_fma(wgp[5], tp, oB);
            tp.x = lE2;  tp.y = e2.x;  oB = __builtin_elementwise_fma(wgp[6], tp, oB);
                                        oB = __builtin_elementwise_fma(wgp[7], e2, oB);
            tp.x = e2.y; tp.y = rE2;   oB = __builtin_elementwise_fma(wgp[8], tp, oB);
        }

        __builtin_nontemporal_store(oA, (v2f*)(obc + (size_t)(2 * g)     * PLANE_B + pb0));
        __builtin_nontemporal_store(oB, (v2f*)(obc + (size_t)(2 * g + 1) * PLANE_B + pb0));
    }
}

extern "C" void kernel_launch(void* const* d_in, const int* in_sizes, int n_in,
                              void* d_out, int out_size, void* d_ws, size_t ws_size,
                              hipStream_t stream)
{
    const float* x  = (const float*)d_in[0];
    const float* w1 = (const float*)d_in[1];
    const float* b1 = (const float*)d_in[2];
    const float* pa = (const float*)d_in[3];
    const float* w2 = (const float*)d_in[4];
    const float* b2 = (const float*)d_in[5];
    float* out  = (float*)d_out;
    float* t_ws = (float*)d_ws;              // 16 * 131072 * 4 B = 8.4 MB

    hipLaunchKernelGGL(conv1_kernel, dim3(TOTPIX / 128), dim3(256), 0, stream,
                       x, w1, b1, pa, t_ws);
    hipLaunchKernelGGL(invol_kernel, dim3(8 * 8 * 32), dim3(256), 0, stream,
                       x, t_ws, w2, b2, out);
}

// Round 11
// 127.459 us; speedup vs baseline: 1.0373x; 1.0094x over previous
//
#include <hip/hip_runtime.h>

#define NPIX (128 * 128)
#define CH 64
#define RMID 16
#define KK 9
#define TOTPIX (8 * NPIX)        // 131072
#define PLANE_B 65536            // bytes per channel plane

typedef float v2f __attribute__((ext_vector_type(2)));

// ---------------- K1: conv1 + PReLU -> t_ws ----------------
// 4 threads per pixel (layer = wave; channels [16L,16L+16)), LDS reduce.
// Grid 2048 blocks XCD-PINNED with the same swizzle as K2 (bq = L&7):
// batch b's x reads and t writes land in XCD b's L2, which is exactly
// where K2 (pinned identically) will look for them. 2048 blocks x 4 waves
// = 32 waves/CU (full), ~50 VGPR, 16 loads in flight per thread.
__global__ __launch_bounds__(256) void conv1_kernel(
    const float* __restrict__ x,
    const float* __restrict__ w1,
    const float* __restrict__ b1,
    const float* __restrict__ prelu_a,
    float* __restrict__ t_ws)
{
    __shared__ float pl[4][64][17];      // [layer][px][r], stride 17 (2/bank = free)

    const int c     = threadIdx.x & 63;  // pixel within chunk
    const int layer = threadIdx.x >> 6;  // 0..3, wave-uniform

    const int L     = blockIdx.x;        // 0..2047
    const int bq    = L & 7;             // batch == XCD pin (matches K2)
    const int chunk = L >> 3;            // 0..255
    const int p     = chunk * 64 + c;
    const int G     = (bq << 14) + p;

    const float* xp = x + (size_t)bq * CH * NPIX + (size_t)(16 * layer) * NPIX + p;

    float xv[16];
#pragma unroll
    for (int k = 0; k < 16; ++k) xv[k] = xp[(size_t)k * NPIX];   // all in flight

    float t[RMID];
#pragma unroll
    for (int r = 0; r < RMID; ++r) t[r] = (layer == 0) ? b1[r] : 0.f;

#pragma unroll
    for (int k = 0; k < 16; ++k) {
#pragma unroll
        for (int r = 0; r < RMID; ++r)
            t[r] = fmaf(w1[r * CH + 16 * layer + k], xv[k], t[r]);  // uniform -> s_load
    }
#pragma unroll
    for (int r = 0; r < RMID; ++r) pl[layer][c][r] = t[r];
    __syncthreads();

    const float a  = prelu_a[0];
    const int   r0 = 4 * layer;
#pragma unroll
    for (int i = 0; i < 4; ++i) {
        float v = pl[0][c][r0 + i] + pl[1][c][r0 + i]
                + pl[2][c][r0 + i] + pl[3][c][r0 + i];
        v = (v >= 0.f) ? v : a * v;
        t_ws[(size_t)(r0 + i) * TOTPIX + G] = v;                 // coalesced
    }
}

// ---------------- K2: conv2 (weight gen) + involution ---------------- (r10)
// Pixel-pair threads: wave = one image row (64 lanes x 2 px). Own-column
// loads (dwordx2) + lane shuffles for +-1 column taps; borders zero-masked.
// XCD-pinned grid: bq=L&7, gq=(L>>3)&7 (consecutive per XCD), strip=L>>6.
__global__ __launch_bounds__(256) void invol_kernel(
    const float* __restrict__ x,
    const float* __restrict__ t_ws,
    const float* __restrict__ w2,
    const float* __restrict__ b2,
    float* __restrict__ out)
{
    const int c    = threadIdx.x & 63;    // column-pair id (cols 2c, 2c+1)
    const int rsub = threadIdx.x >> 6;    // 0..3: row within strip; wave-uniform

    const int L     = blockIdx.x;         // 0..2047
    const int bq    = L & 7;              // batch == XCD pin
    const int gq    = (L >> 3) & 7;       // group-quad (consecutive on one XCD)
    const int strip = L >> 6;             // 0..31 (4 rows each)

    const int hq   = 4 * strip + rsub;
    const int col0 = 2 * c;
    const int p0   = hq * 128 + col0;

    // ---- t for both pixels, transposed to px-major r-pairs ----
    const int G0 = (bq << 14) + p0;
    v2f trA[8], trB[8];
#pragma unroll
    for (int i = 0; i < 8; ++i) {
        const v2f va = *(const v2f*)(t_ws + (size_t)(2 * i)     * TOTPIX + G0);
        const v2f vb = *(const v2f*)(t_ws + (size_t)(2 * i + 1) * TOTPIX + G0);
        trA[i].x = va.x; trA[i].y = vb.x;
        trB[i].x = va.y; trB[i].y = vb.y;
    }

    // ---- masks (border zero-padding) ----
    const float rm0 = (hq > 0)   ? 1.f : 0.f;
    const float rm2 = (hq < 127) ? 1.f : 0.f;
    const float mL  = (c > 0)    ? 1.f : 0.f;
    const float mR  = (c < 63)   ? 1.f : 0.f;
    v2f mk[KK];
#pragma unroll
    for (int i = 0; i < 3; ++i) {
        const float rmv = (i == 0) ? rm0 : (i == 2) ? rm2 : 1.f;
        mk[i * 3 + 0].x = rmv * mL;  mk[i * 3 + 0].y = rmv;
        mk[i * 3 + 1].x = rmv;       mk[i * 3 + 1].y = rmv;
        mk[i * 3 + 2].x = rmv;       mk[i * 3 + 2].y = rmv * mR;
    }

    const int ro0 = (hq > 0)   ? -512 : 0;
    const int ro2 = (hq < 127) ?  512 : 0;

    const char* xbc = (const char*)(x   + (size_t)bq * CH * NPIX);
    char*       obc = (char*)      (out + (size_t)bq * CH * NPIX);
    const int   pb0 = 4 * p0;

#pragma unroll
    for (int gi = 0; gi < 4; ++gi) {
        const int g = 4 * gq + gi;                        // block-uniform
        const char* c0p = xbc + (size_t)(2 * g) * PLANE_B;
        const char* c1p = c0p + PLANE_B;

        const v2f a0 = *(const v2f*)(c0p + (size_t)(pb0 + ro0));
        const v2f a1 = *(const v2f*)(c0p + (size_t)pb0);
        const v2f a2 = *(const v2f*)(c0p + (size_t)(pb0 + ro2));
        const v2f e0 = *(const v2f*)(c1p + (size_t)(pb0 + ro0));
        const v2f e1 = *(const v2f*)(c1p + (size_t)pb0);
        const v2f e2 = *(const v2f*)(c1p + (size_t)(pb0 + ro2));

        // -- weight gen: pk over r-pairs, per pixel (covers load latency) --
        v2f wgp[KK];
#pragma unroll
        for (int k = 0; k < KK; ++k) {
            const v2f* w2r2 = (const v2f*)(w2 + (g * KK + k) * RMID);
            v2f accA, accB;
            accA.x = b2[g * KK + k]; accA.y = 0.f;
            accB = accA;
#pragma unroll
            for (int r = 0; r < RMID / 2; ++r) {
                accA = __builtin_elementwise_fma(w2r2[r], trA[r], accA);
                accB = __builtin_elementwise_fma(w2r2[r], trB[r], accB);
            }
            v2f wk;
            wk.x = accA.x + accA.y;
            wk.y = accB.x + accB.y;
            wgp[k] = wk * mk[k];
        }

        // -- neighbor columns via lane shuffle (wave = full row) --
        const float lA0 = __shfl_up(a0.y, 1), rA0 = __shfl_down(a0.x, 1);
        const float lA1 = __shfl_up(a1.y, 1), rA1 = __shfl_down(a1.x, 1);
        const float lA2 = __shfl_up(a2.y, 1), rA2 = __shfl_down(a2.x, 1);
        const float lE0 = __shfl_up(e0.y, 1), rE0 = __shfl_down(e0.x, 1);
        const float lE1 = __shfl_up(e1.y, 1), rE1 = __shfl_down(e1.x, 1);
        const float lE2 = __shfl_up(e2.y, 1), rE2 = __shfl_down(e2.x, 1);

        // -- combine --
        v2f oA; oA.x = 0.f; oA.y = 0.f;
        v2f oB = oA;
        {
            v2f tp;
            tp.x = lA0;  tp.y = a0.x;  oA = __builtin_elementwise_fma(wgp[0], tp, oA);
                                        oA = __builtin_elementwise_fma(wgp[1], a0, oA);
            tp.x = a0.y; tp.y = rA0;   oA = __builtin_elementwise_fma(wgp[2], tp, oA);
            tp.x = lA1;  tp.y = a1.x;  oA = __builtin_elementwise_fma(wgp[3], tp, oA);
                                        oA = __builtin_elementwise_fma(wgp[4], a1, oA);
            tp.x = a1.y; tp.y = rA1;   oA = __builtin_elementwise_fma(wgp[5], tp, oA);
            tp.x = lA2;  tp.y = a2.x;  oA = __builtin_elementwise_fma(wgp[6], tp, oA);
                                        oA = __builtin_elementwise_fma(wgp[7], a2, oA);
            tp.x = a2.y; tp.y = rA2;   oA = __builtin_elementwise_fma(wgp[8], tp, oA);

            tp.x = lE0;  tp.y = e0.x;  oB = __builtin_elementwise_fma(wgp[0], tp, oB);
                                        oB = __builtin_elementwise_fma(wgp[1], e0, oB);
            tp.x = e0.y; tp.y = rE0;   oB = __builtin_elementwise_fma(wgp[2], tp, oB);
            tp.x = lE1;  tp.y = e1.x;  oB = __builtin_elementwise_fma(wgp[3], tp, oB);
                                        oB = __builtin_elementwise_fma(wgp[4], e1, oB);
            tp.x = e1.y; tp.y = rE1;   oB = __builtin_elementwise_fma(wgp[5], tp, oB);
            tp.x = lE2;  tp.y = e2.x;  oB = __builtin_elementwise_fma(wgp[6], tp, oB);
                                        oB = __builtin_elementwise_fma(wgp[7], e2, oB);
            tp.x = e2.y; tp.y = rE2;   oB = __builtin_elementwise_fma(wgp[8], tp, oB);
        }

        __builtin_nontemporal_store(oA, (v2f*)(obc + (size_t)(2 * g)     * PLANE_B + pb0));
        __builtin_nontemporal_store(oB, (v2f*)(obc + (size_t)(2 * g + 1) * PLANE_B + pb0));
    }
}

extern "C" void kernel_launch(void* const* d_in, const int* in_sizes, int n_in,
                              void* d_out, int out_size, void* d_ws, size_t ws_size,
                              hipStream_t stream)
{
    const float* x  = (const float*)d_in[0];
    const float* w1 = (const float*)d_in[1];
    const float* b1 = (const float*)d_in[2];
    const float* pa = (const float*)d_in[3];
    const float* w2 = (const float*)d_in[4];
    const float* b2 = (const float*)d_in[5];
    float* out  = (float*)d_out;
    float* t_ws = (float*)d_ws;              // 16 * 131072 * 4 B = 8.4 MB

    hipLaunchKernelGGL(conv1_kernel, dim3(2048), dim3(256), 0, stream,
                       x, w1, b1, pa, t_ws);
    hipLaunchKernelGGL(invol_kernel, dim3(8 * 8 * 32), dim3(256), 0, stream,
                       x, t_ws, w2, b2, out);
}

// Round 12
// 123.835 us; speedup vs baseline: 1.0677x; 1.0293x over previous
//
#include <hip/hip_runtime.h>

#define NPIX (128 * 128)
#define CH 64
#define RMID 16
#define KK 9
#define TOTPIX (8 * NPIX)        // 131072
#define PLANE_B 65536            // bytes per channel plane

typedef float v2f __attribute__((ext_vector_type(2)));

// ---------------- K1: conv1 + PReLU -> t_ws ----------------
// Pixel-pair threads, 4-way channel split (layer = wave, 16 ch each), LDS
// v2f reduce. t_ws layout: PIXEL-MAJOR [G][16] (16 contiguous floats per
// pixel) -> K1 stores 2 dwordx4/thread-layer, K2 reads 4 dwordx4/pixel.
// Grid 1024 blocks XCD-pinned (bq = L&7, same as K2).
__global__ __launch_bounds__(256) void conv1_kernel(
    const float* __restrict__ x,
    const float* __restrict__ w1,
    const float* __restrict__ b1,
    const float* __restrict__ prelu_a,
    float* __restrict__ t_ws)
{
    __shared__ v2f pl[4][64][17];        // [layer][pair][r], pad 17

    const int c     = threadIdx.x & 63;  // pair id within block
    const int layer = threadIdx.x >> 6;  // 0..3, wave-uniform

    const int L     = blockIdx.x;        // 0..1023
    const int bq    = L & 7;             // batch == XCD pin (matches K2)
    const int chunk = L >> 3;            // 0..127
    const int p0    = chunk * 128 + 2 * c;
    const int G0    = (bq << 14) + p0;

    const float* xp = x + (size_t)bq * CH * NPIX + (size_t)(16 * layer) * NPIX + p0;

    v2f xv[16];
#pragma unroll
    for (int k = 0; k < 16; ++k) xv[k] = *(const v2f*)(xp + (size_t)k * NPIX);  // all in flight

    v2f t2[RMID];
#pragma unroll
    for (int r = 0; r < RMID; ++r) {
        const float b = (layer == 0) ? b1[r] : 0.f;
        t2[r].x = b; t2[r].y = b;
    }

#pragma unroll
    for (int k = 0; k < 16; ++k) {
#pragma unroll
        for (int r = 0; r < RMID; ++r) {
            const float w = w1[r * CH + 16 * layer + k];   // uniform -> s_load
            v2f wv; wv.x = w; wv.y = w;
            t2[r] = __builtin_elementwise_fma(wv, xv[k], t2[r]);   // v_pk_fma_f32
        }
    }
#pragma unroll
    for (int r = 0; r < RMID; ++r) pl[layer][c][r] = t2[r];
    __syncthreads();

    const float a  = prelu_a[0];
    const int   r0 = 4 * layer;
    float s0[4], s1[4];                  // px0 / px1 values for rows r0..r0+3
#pragma unroll
    for (int i = 0; i < 4; ++i) {
        const v2f v = pl[0][c][r0 + i] + pl[1][c][r0 + i]
                    + pl[2][c][r0 + i] + pl[3][c][r0 + i];
        const float v0 = (v.x >= 0.f) ? v.x : a * v.x;
        const float v1 = (v.y >= 0.f) ? v.y : a * v.y;
        s0[i] = v0; s1[i] = v1;
    }
    // pixel-major stores: px0 rows r0..r0+3 contiguous, same for px1
    float* tb = t_ws + (size_t)G0 * 16 + r0;
    *(float4*)(tb)      = make_float4(s0[0], s0[1], s0[2], s0[3]);
    *(float4*)(tb + 16) = make_float4(s1[0], s1[1], s1[2], s1[3]);
}

// ---------------- K2: conv2 (weight gen) + involution ----------------
// Pixel-pair threads, wave = one image row. TWO groups per thread.
// Grid 4096 = 8 bq x 16 group-pair (fastest per XCD) x 32 strip (4 rows).
// ALL vmem loads (8 t dwordx4-equivalents + 12 tap dwordx2) issued before
// any math -> one vmcnt drain per thread. +-1 column taps via lane shuffle.
__global__ __launch_bounds__(256) void invol_kernel(
    const float* __restrict__ x,
    const float* __restrict__ t_ws,
    const float* __restrict__ w2,
    const float* __restrict__ b2,
    float* __restrict__ out)
{
    const int c    = threadIdx.x & 63;    // column-pair id (cols 2c, 2c+1)
    const int rsub = threadIdx.x >> 6;    // row within strip, wave-uniform

    const int L     = blockIdx.x;         // 0..4095
    const int bq    = L & 7;              // batch == XCD pin
    const int gp    = (L >> 3) & 15;      // group-pair (fastest per XCD -> t reuse)
    const int strip = L >> 7;             // 0..31 (4 rows each)

    const int hq  = 4 * strip + rsub;
    const int p0  = hq * 128 + 2 * c;
    const int G0  = (bq << 14) + p0;
    const int pb0 = 4 * p0;

    const int g0 = 2 * gp, g1 = 2 * gp + 1;

    // ---- issue ALL loads first ----
    const v2f* tb = (const v2f*)(t_ws + (size_t)G0 * 16);
    v2f trA[8], trB[8];                   // trA[i] = (t_{2i}, t_{2i+1})(px0)
#pragma unroll
    for (int i = 0; i < 8; ++i) { trA[i] = tb[i]; trB[i] = tb[8 + i]; }

    const int ro0 = (hq > 0)   ? -512 : 0;
    const int ro2 = (hq < 127) ?  512 : 0;
    const char* xbc  = (const char*)(x + (size_t)bq * CH * NPIX);
    const char* cp00 = xbc + (size_t)(2 * g0) * PLANE_B;   // group0 plane0
    const char* cp01 = cp00 + PLANE_B;                     // group0 plane1
    const char* cp10 = xbc + (size_t)(2 * g1) * PLANE_B;   // group1 plane0
    const char* cp11 = cp10 + PLANE_B;

    const v2f a0 = *(const v2f*)(cp00 + (size_t)(pb0 + ro0));
    const v2f a1 = *(const v2f*)(cp00 + (size_t)pb0);
    const v2f a2 = *(const v2f*)(cp00 + (size_t)(pb0 + ro2));
    const v2f e0 = *(const v2f*)(cp01 + (size_t)(pb0 + ro0));
    const v2f e1 = *(const v2f*)(cp01 + (size_t)pb0);
    const v2f e2 = *(const v2f*)(cp01 + (size_t)(pb0 + ro2));
    const v2f f0 = *(const v2f*)(cp10 + (size_t)(pb0 + ro0));
    const v2f f1 = *(const v2f*)(cp10 + (size_t)pb0);
    const v2f f2 = *(const v2f*)(cp10 + (size_t)(pb0 + ro2));
    const v2f h0 = *(const v2f*)(cp11 + (size_t)(pb0 + ro0));
    const v2f h1 = *(const v2f*)(cp11 + (size_t)pb0);
    const v2f h2 = *(const v2f*)(cp11 + (size_t)(pb0 + ro2));

    // ---- masks (border zero-padding) ----
    const float rm0 = (hq > 0)   ? 1.f : 0.f;
    const float rm2 = (hq < 127) ? 1.f : 0.f;
    const float mL  = (c > 0)    ? 1.f : 0.f;
    const float mR  = (c < 63)   ? 1.f : 0.f;
    v2f mk[KK];
#pragma unroll
    for (int i = 0; i < 3; ++i) {
        const float rmv = (i == 0) ? rm0 : (i == 2) ? rm2 : 1.f;
        mk[i * 3 + 0].x = rmv * mL;  mk[i * 3 + 0].y = rmv;
        mk[i * 3 + 1].x = rmv;       mk[i * 3 + 1].y = rmv;
        mk[i * 3 + 2].x = rmv;       mk[i * 3 + 2].y = rmv * mR;
    }

    char* obc = (char*)(out + (size_t)bq * CH * NPIX);

#pragma unroll
    for (int gi = 0; gi < 2; ++gi) {
        const int g = (gi == 0) ? g0 : g1;
        const v2f A0 = gi ? f0 : a0, A1 = gi ? f1 : a1, A2 = gi ? f2 : a2;
        const v2f E0 = gi ? h0 : e0, E1 = gi ? h1 : e1, E2 = gi ? h2 : e2;

        // -- weight gen: pk over r-pairs per pixel --
        v2f wgp[KK];
#pragma unroll
        for (int k = 0; k < KK; ++k) {
            const v2f* w2r2 = (const v2f*)(w2 + (g * KK + k) * RMID);  // uniform
            v2f accA, accB;
            accA.x = b2[g * KK + k]; accA.y = 0.f;
            accB = accA;
#pragma unroll
            for (int r = 0; r < RMID / 2; ++r) {
                accA = __builtin_elementwise_fma(w2r2[r], trA[r], accA);
                accB = __builtin_elementwise_fma(w2r2[r], trB[r], accB);
            }
            v2f wk;
            wk.x = accA.x + accA.y;
            wk.y = accB.x + accB.y;
            wgp[k] = wk * mk[k];
        }

        // -- neighbor columns via lane shuffle (wave = full row) --
        const float lA0 = __shfl_up(A0.y, 1), rA0 = __shfl_down(A0.x, 1);
        const float lA1 = __shfl_up(A1.y, 1), rA1 = __shfl_down(A1.x, 1);
        const float lA2 = __shfl_up(A2.y, 1), rA2 = __shfl_down(A2.x, 1);
        const float lE0 = __shfl_up(E0.y, 1), rE0 = __shfl_down(E0.x, 1);
        const float lE1 = __shfl_up(E1.y, 1), rE1 = __shfl_down(E1.x, 1);
        const float lE2 = __shfl_up(E2.y, 1), rE2 = __shfl_down(E2.x, 1);

        // -- combine --
        v2f oA; oA.x = 0.f; oA.y = 0.f;
        v2f oB = oA;
        v2f tp;
        tp.x = lA0;  tp.y = A0.x;  oA = __builtin_elementwise_fma(wgp[0], tp, oA);
                                    oA = __builtin_elementwise_fma(wgp[1], A0, oA);
        tp.x = A0.y; tp.y = rA0;   oA = __builtin_elementwise_fma(wgp[2], tp, oA);
        tp.x = lA1;  tp.y = A1.x;  oA = __builtin_elementwise_fma(wgp[3], tp, oA);
                                    oA = __builtin_elementwise_fma(wgp[4], A1, oA);
        tp.x = A1.y; tp.y = rA1;   oA = __builtin_elementwise_fma(wgp[5], tp, oA);
        tp.x = lA2;  tp.y = A2.x;  oA = __builtin_elementwise_fma(wgp[6], tp, oA);
                                    oA = __builtin_elementwise_fma(wgp[7], A2, oA);
        tp.x = A2.y; tp.y = rA2;   oA = __builtin_elementwise_fma(wgp[8], tp, oA);

        tp.x = lE0;  tp.y = E0.x;  oB = __builtin_elementwise_fma(wgp[0], tp, oB);
                                    oB = __builtin_elementwise_fma(wgp[1], E0, oB);
        tp.x = E0.y; tp.y = rE0;   oB = __builtin_elementwise_fma(wgp[2], tp, oB);
        tp.x = lE1;  tp.y = E1.x;  oB = __builtin_elementwise_fma(wgp[3], tp, oB);
                                    oB = __builtin_elementwise_fma(wgp[4], E1, oB);
        tp.x = E1.y; tp.y = rE1;   oB = __builtin_elementwise_fma(wgp[5], tp, oB);
        tp.x = lE2;  tp.y = E2.x;  oB = __builtin_elementwise_fma(wgp[6], tp, oB);
                                    oB = __builtin_elementwise_fma(wgp[7], E2, oB);
        tp.x = E2.y; tp.y = rE2;   oB = __builtin_elementwise_fma(wgp[8], tp, oB);

        __builtin_nontemporal_store(oA, (v2f*)(obc + (size_t)(2 * g)     * PLANE_B + pb0));
        __builtin_nontemporal_store(oB, (v2f*)(obc + (size_t)(2 * g + 1) * PLANE_B + pb0));
    }
}

extern "C" void kernel_launch(void* const* d_in, const int* in_sizes, int n_in,
                              void* d_out, int out_size, void* d_ws, size_t ws_size,
                              hipStream_t stream)
{
    const float* x  = (const float*)d_in[0];
    const float* w1 = (const float*)d_in[1];
    const float* b1 = (const float*)d_in[2];
    const float* pa = (const float*)d_in[3];
    const float* w2 = (const float*)d_in[4];
    const float* b2 = (const float*)d_in[5];
    float* out  = (float*)d_out;
    float* t_ws = (float*)d_ws;              // [G][16] pixel-major, 8.4 MB

    hipLaunchKernelGGL(conv1_kernel, dim3(1024), dim3(256), 0, stream,
                       x, w1, b1, pa, t_ws);
    hipLaunchKernelGGL(invol_kernel, dim3(4096), dim3(256), 0, stream,
                       x, t_ws, w2, b2, out);
}

// Round 13
// 123.234 us; speedup vs baseline: 1.0729x; 1.0049x over previous
//
#include <hip/hip_runtime.h>

#define NPIX (128 * 128)
#define CH 64
#define RMID 16
#define KK 9
#define TOTPIX (8 * NPIX)        // 131072
#define PLANE_B 65536            // bytes per channel plane

typedef float v2f __attribute__((ext_vector_type(2)));

// ---------------- K1: conv1 + PReLU -> t_ws ---------------- (r12, unchanged)
// Pixel-pair threads, 4-way channel split (layer = wave, 16 ch each), LDS
// v2f reduce. t_ws pixel-major [G][16]. XCD-pinned (bq = L&7, matches K2).
__global__ __launch_bounds__(256) void conv1_kernel(
    const float* __restrict__ x,
    const float* __restrict__ w1,
    const float* __restrict__ b1,
    const float* __restrict__ prelu_a,
    float* __restrict__ t_ws)
{
    __shared__ v2f pl[4][64][17];

    const int c     = threadIdx.x & 63;
    const int layer = threadIdx.x >> 6;

    const int L     = blockIdx.x;        // 0..1023
    const int bq    = L & 7;
    const int chunk = L >> 3;
    const int p0    = chunk * 128 + 2 * c;
    const int G0    = (bq << 14) + p0;

    const float* xp = x + (size_t)bq * CH * NPIX + (size_t)(16 * layer) * NPIX + p0;

    v2f xv[16];
#pragma unroll
    for (int k = 0; k < 16; ++k) xv[k] = *(const v2f*)(xp + (size_t)k * NPIX);

    v2f t2[RMID];
#pragma unroll
    for (int r = 0; r < RMID; ++r) {
        const float b = (layer == 0) ? b1[r] : 0.f;
        t2[r].x = b; t2[r].y = b;
    }

#pragma unroll
    for (int k = 0; k < 16; ++k) {
#pragma unroll
        for (int r = 0; r < RMID; ++r) {
            const float w = w1[r * CH + 16 * layer + k];   // uniform -> s_load
            v2f wv; wv.x = w; wv.y = w;
            t2[r] = __builtin_elementwise_fma(wv, xv[k], t2[r]);
        }
    }
#pragma unroll
    for (int r = 0; r < RMID; ++r) pl[layer][c][r] = t2[r];
    __syncthreads();

    const float a  = prelu_a[0];
    const int   r0 = 4 * layer;
    float s0[4], s1[4];
#pragma unroll
    for (int i = 0; i < 4; ++i) {
        const v2f v = pl[0][c][r0 + i] + pl[1][c][r0 + i]
                    + pl[2][c][r0 + i] + pl[3][c][r0 + i];
        s0[i] = (v.x >= 0.f) ? v.x : a * v.x;
        s1[i] = (v.y >= 0.f) ? v.y : a * v.y;
    }
    float* tb = t_ws + (size_t)G0 * 16 + r0;
    *(float4*)(tb)      = make_float4(s0[0], s0[1], s0[2], s0[3]);
    *(float4*)(tb + 16) = make_float4(s1[0], s1[1], s1[2], s1[3]);
}

// ---------------- K2: conv2 (weight gen) + involution ----------------
// Pixel-pair threads, wave = one image row, 2 groups/thread but SEQUENTIAL:
// per group load 6 taps -> gen (198 VALU, covers tap latency) -> combine ->
// store. Only one group's taps live at a time; no mk array (rows masked by
// 4 pk-muls on taps, columns by 6 scalar muls on wgp). Target <=95 VGPR ->
// 5-6 waves/SIMD (r12 was ~120 VGPR -> 4). XCD-pinned: bq=L&7, gp fastest.
__global__ __launch_bounds__(256) void invol_kernel(
    const float* __restrict__ x,
    const float* __restrict__ t_ws,
    const float* __restrict__ w2,
    const float* __restrict__ b2,
    float* __restrict__ out)
{
    const int c    = threadIdx.x & 63;    // column-pair id (cols 2c, 2c+1)
    const int rsub = threadIdx.x >> 6;    // row within strip, wave-uniform

    const int L     = blockIdx.x;         // 0..4095
    const int bq    = L & 7;              // batch == XCD pin
    const int gp    = (L >> 3) & 15;      // group-pair (fastest per XCD)
    const int strip = L >> 7;             // 0..31

    const int hq  = 4 * strip + rsub;
    const int p0  = hq * 128 + 2 * c;
    const int G0  = (bq << 14) + p0;
    const int pb0 = 4 * p0;

    // t loads (8 x b64, contiguous) — issued first, in flight across setup
    const v2f* tb = (const v2f*)(t_ws + (size_t)G0 * 16);
    v2f trA[8], trB[8];
#pragma unroll
    for (int i = 0; i < 8; ++i) { trA[i] = tb[i]; trB[i] = tb[8 + i]; }

    // border masks / clamped row offsets
    const float rm0 = (hq > 0)   ? 1.f : 0.f;
    const float rm2 = (hq < 127) ? 1.f : 0.f;
    const float mL  = (c > 0)    ? 1.f : 0.f;
    const float mR  = (c < 63)   ? 1.f : 0.f;
    const int   ro0 = (hq > 0)   ? -512 : 0;
    const int   ro2 = (hq < 127) ?  512 : 0;

    const char* xbc = (const char*)(x + (size_t)bq * CH * NPIX);
    char*       obc = (char*)(out + (size_t)bq * CH * NPIX);

#pragma unroll
    for (int gi = 0; gi < 2; ++gi) {
        const int g = 2 * gp + gi;                        // block-uniform
        const char* cp0 = xbc + (size_t)(2 * g) * PLANE_B;
        const char* cp1 = cp0 + PLANE_B;

        // -- this group's 6 taps (b64) --
        v2f A0 = *(const v2f*)(cp0 + (size_t)(pb0 + ro0));
        v2f A1 = *(const v2f*)(cp0 + (size_t)pb0);
        v2f A2 = *(const v2f*)(cp0 + (size_t)(pb0 + ro2));
        v2f E0 = *(const v2f*)(cp1 + (size_t)(pb0 + ro0));
        v2f E1 = *(const v2f*)(cp1 + (size_t)pb0);
        v2f E2 = *(const v2f*)(cp1 + (size_t)(pb0 + ro2));

        // -- gen 9 weights (covers tap latency; t already resident) --
        v2f wgp[KK];
#pragma unroll
        for (int k = 0; k < KK; ++k) {
            const v2f* w2r2 = (const v2f*)(w2 + (g * KK + k) * RMID);  // uniform
            v2f accA, accB;
            accA.x = b2[g * KK + k]; accA.y = 0.f;
            accB = accA;
#pragma unroll
            for (int r = 0; r < RMID / 2; ++r) {
                accA = __builtin_elementwise_fma(w2r2[r], trA[r], accA);
                accB = __builtin_elementwise_fma(w2r2[r], trB[r], accB);
            }
            wgp[k].x = accA.x + accA.y;
            wgp[k].y = accB.x + accB.y;
        }
        // column masks: px0 left tap invalid at c==0, px1 right tap at c==63
        wgp[0].x *= mL;  wgp[3].x *= mL;  wgp[6].x *= mL;
        wgp[2].y *= mR;  wgp[5].y *= mR;  wgp[8].y *= mR;
        // row masks folded into the taps (4 pk muls)
        { v2f r0v; r0v.x = rm0; r0v.y = rm0;  A0 *= r0v;  E0 *= r0v; }
        { v2f r2v; r2v.x = rm2; r2v.y = rm2;  A2 *= r2v;  E2 *= r2v; }

        // -- neighbor columns via lane shuffle (wave = full row) --
        const float lA0 = __shfl_up(A0.y, 1), rA0 = __shfl_down(A0.x, 1);
        const float lA1 = __shfl_up(A1.y, 1), rA1 = __shfl_down(A1.x, 1);
        const float lA2 = __shfl_up(A2.y, 1), rA2 = __shfl_down(A2.x, 1);
        const float lE0 = __shfl_up(E0.y, 1), rE0 = __shfl_down(E0.x, 1);
        const float lE1 = __shfl_up(E1.y, 1), rE1 = __shfl_down(E1.x, 1);
        const float lE2 = __shfl_up(E2.y, 1), rE2 = __shfl_down(E2.x, 1);

        // -- combine --
        v2f oA; oA.x = 0.f; oA.y = 0.f;
        v2f oB = oA;
        v2f tp;
        tp.x = lA0;  tp.y = A0.x;  oA = __builtin_elementwise_fma(wgp[0], tp, oA);
                                    oA = __builtin_elementwise_fma(wgp[1], A0, oA);
        tp.x = A0.y; tp.y = rA0;   oA = __builtin_elementwise_fma(wgp[2], tp, oA);
        tp.x = lA1;  tp.y = A1.x;  oA = __builtin_elementwise_fma(wgp[3], tp, oA);
                                    oA = __builtin_elementwise_fma(wgp[4], A1, oA);
        tp.x = A1.y; tp.y = rA1;   oA = __builtin_elementwise_fma(wgp[5], tp, oA);
        tp.x = lA2;  tp.y = A2.x;  oA = __builtin_elementwise_fma(wgp[6], tp, oA);
                                    oA = __builtin_elementwise_fma(wgp[7], A2, oA);
        tp.x = A2.y; tp.y = rA2;   oA = __builtin_elementwise_fma(wgp[8], tp, oA);

        tp.x = lE0;  tp.y = E0.x;  oB = __builtin_elementwise_fma(wgp[0], tp, oB);
                                    oB = __builtin_elementwise_fma(wgp[1], E0, oB);
        tp.x = E0.y; tp.y = rE0;   oB = __builtin_elementwise_fma(wgp[2], tp, oB);
        tp.x = lE1;  tp.y = E1.x;  oB = __builtin_elementwise_fma(wgp[3], tp, oB);
                                    oB = __builtin_elementwise_fma(wgp[4], E1, oB);
        tp.x = E1.y; tp.y = rE1;   oB = __builtin_elementwise_fma(wgp[5], tp, oB);
        tp.x = lE2;  tp.y = E2.x;  oB = __builtin_elementwise_fma(wgp[6], tp, oB);
                                    oB = __builtin_elementwise_fma(wgp[7], E2, oB);
        tp.x = E2.y; tp.y = rE2;   oB = __builtin_elementwise_fma(wgp[8], tp, oB);

        __builtin_nontemporal_store(oA, (v2f*)(obc + (size_t)(2 * g)     * PLANE_B + pb0));
        __builtin_nontemporal_store(oB, (v2f*)(obc + (size_t)(2 * g + 1) * PLANE_B + pb0));
    }
}

extern "C" void kernel_launch(void* const* d_in, const int* in_sizes, int n_in,
                              void* d_out, int out_size, void* d_ws, size_t ws_size,
                              hipStream_t stream)
{
    const float* x  = (const float*)d_in[0];
    const float* w1 = (const float*)d_in[1];
    const float* b1 = (const float*)d_in[2];
    const float* pa = (const float*)d_in[3];
    const float* w2 = (const float*)d_in[4];
    const float* b2 = (const float*)d_in[5];
    float* out  = (float*)d_out;
    float* t_ws = (float*)d_ws;              // [G][16] pixel-major, 8.4 MB

    hipLaunchKernelGGL(conv1_kernel, dim3(1024), dim3(256), 0, stream,
                       x, w1, b1, pa, t_ws);
    hipLaunchKernelGGL(invol_kernel, dim3(4096), dim3(256), 0, stream,
                       x, t_ws, w2, b2, out);
}

// Round 14
// 121.093 us; speedup vs baseline: 1.0918x; 1.0177x over previous
//
#include <hip/hip_runtime.h>

#define NPIX (128 * 128)
#define CH 64
#define RMID 16
#define KK 9
#define PLANE_B 65536            // bytes per channel plane

typedef float v2f __attribute__((ext_vector_type(2)));

// Single fused kernel. Grid 1024 = 8 bq (XCD pin, L&7) x 4 group-octets x
// 32 strips. Block = 256 thr = 4 rows x 64 col-pairs; wave = one image row.
// Each thread: conv1+PReLU for its 2 px ENTIRELY IN REGISTERS (t2[16] v2f,
// pixel-pair layout; conv1 duplicated x4 across octets — +3 us VALU buys
// -50 MB HBM: no t_ws round-trip, taps hit L1/L2 behind the conv1 reads),
// then 8 groups: 6 taps -> 144-pk gen (pixel-pair, no hadds) -> shuffle
// neighbors -> combine -> nt store. No LDS, no barrier, no min-waves bound
// (r7 lesson: capping VGPRs spills; live set ~100 VGPR).
__global__ __launch_bounds__(256) void invol_fused(
    const float* __restrict__ x,
    const float* __restrict__ w1,
    const float* __restrict__ b1,
    const float* __restrict__ prelu_a,
    const float* __restrict__ w2,
    const float* __restrict__ b2,
    float* __restrict__ out)
{
    const int c    = threadIdx.x & 63;    // column-pair id (cols 2c, 2c+1)
    const int rsub = threadIdx.x >> 6;    // row within strip, wave-uniform

    const int L     = blockIdx.x;         // 0..1023
    const int bq    = L & 7;              // batch == XCD pin
    const int go    = (L >> 3) & 3;       // group-octet (consecutive per XCD)
    const int strip = L >> 5;             // 0..31 (4 rows)

    const int hq  = 4 * strip + rsub;
    const int p0  = hq * 128 + 2 * c;
    const int pb0 = 4 * p0;

    const float* xb  = x + (size_t)bq * CH * NPIX;
    const char*  xbc = (const char*)xb;

    // ---- conv1 (pixel-pair layout): t2[r] = (t_r(px0), t_r(px1)) ----
    v2f t2[RMID];
#pragma unroll
    for (int r = 0; r < RMID; ++r) {
        const float b = b1[r];
        t2[r].x = b; t2[r].y = b;
    }
    const float* xp = xb + p0;
#pragma unroll
    for (int cc = 0; cc < CH; cc += 8) {
        v2f xv[8];
#pragma unroll
        for (int k = 0; k < 8; ++k)
            xv[k] = *(const v2f*)(xp + (size_t)(cc + k) * NPIX);   // 8 b64 in flight
#pragma unroll
        for (int k = 0; k < 8; ++k) {
#pragma unroll
            for (int r = 0; r < RMID; ++r) {
                const float w = w1[r * CH + cc + k];               // uniform -> s_load
                v2f wv; wv.x = w; wv.y = w;
                t2[r] = __builtin_elementwise_fma(wv, xv[k], t2[r]);  // v_pk_fma_f32
            }
        }
    }
    // PReLU: t = max(t,0) + a*min(t,0)  (3 pk ops per r-pair)
    {
        const float a = prelu_a[0];
        v2f av; av.x = a; av.y = a;
        v2f z;  z.x = 0.f; z.y = 0.f;
#pragma unroll
        for (int r = 0; r < RMID; ++r) {
            const v2f pos = __builtin_elementwise_max(t2[r], z);
            const v2f neg = __builtin_elementwise_min(t2[r], z);
            t2[r] = __builtin_elementwise_fma(av, neg, pos);
        }
    }

    // ---- border masks / clamped row offsets ----
    const float rm0 = (hq > 0)   ? 1.f : 0.f;
    const float rm2 = (hq < 127) ? 1.f : 0.f;
    const float mL  = (c > 0)    ? 1.f : 0.f;
    const float mR  = (c < 63)   ? 1.f : 0.f;
    const int   ro0 = (hq > 0)   ? -512 : 0;
    const int   ro2 = (hq < 127) ?  512 : 0;

    char* obc = (char*)(out + (size_t)bq * CH * NPIX);

#pragma unroll
    for (int gi = 0; gi < 8; ++gi) {
        const int g = 8 * go + gi;                        // block-uniform
        const char* cp0 = xbc + (size_t)(2 * g) * PLANE_B;
        const char* cp1 = cp0 + PLANE_B;

        // -- this group's 6 taps (b64; L1/L2 hits behind the conv1 reads) --
        v2f A0 = *(const v2f*)(cp0 + (size_t)(pb0 + ro0));
        v2f A1 = *(const v2f*)(cp0 + (size_t)pb0);
        v2f A2 = *(const v2f*)(cp0 + (size_t)(pb0 + ro2));
        v2f E0 = *(const v2f*)(cp1 + (size_t)(pb0 + ro0));
        v2f E1 = *(const v2f*)(cp1 + (size_t)pb0);
        v2f E2 = *(const v2f*)(cp1 + (size_t)(pb0 + ro2));

        // -- gen 9 weights, pixel-pair layout: 16 pk per k, no hadds --
        v2f wgp[KK];
#pragma unroll
        for (int k = 0; k < KK; ++k) {
            const float* w2r = w2 + (g * KK + k) * RMID;  // uniform -> s_load
            const float bb = b2[g * KK + k];
            v2f acc; acc.x = bb; acc.y = bb;
#pragma unroll
            for (int r = 0; r < RMID; ++r) {
                const float w = w2r[r];
                v2f wv; wv.x = w; wv.y = w;
                acc = __builtin_elementwise_fma(wv, t2[r], acc);
            }
            wgp[k] = acc;
        }
        // column masks: px0 left tap invalid at c==0, px1 right tap at c==63
        wgp[0].x *= mL;  wgp[3].x *= mL;  wgp[6].x *= mL;
        wgp[2].y *= mR;  wgp[5].y *= mR;  wgp[8].y *= mR;
        // row masks folded into the taps (4 pk muls)
        { v2f r0v; r0v.x = rm0; r0v.y = rm0;  A0 *= r0v;  E0 *= r0v; }
        { v2f r2v; r2v.x = rm2; r2v.y = rm2;  A2 *= r2v;  E2 *= r2v; }

        // -- neighbor columns via lane shuffle (wave = full row) --
        const float lA0 = __shfl_up(A0.y, 1), rA0 = __shfl_down(A0.x, 1);
        const float lA1 = __shfl_up(A1.y, 1), rA1 = __shfl_down(A1.x, 1);
        const float lA2 = __shfl_up(A2.y, 1), rA2 = __shfl_down(A2.x, 1);
        const float lE0 = __shfl_up(E0.y, 1), rE0 = __shfl_down(E0.x, 1);
        const float lE1 = __shfl_up(E1.y, 1), rE1 = __shfl_down(E1.x, 1);
        const float lE2 = __shfl_up(E2.y, 1), rE2 = __shfl_down(E2.x, 1);

        // -- combine --
        v2f oA; oA.x = 0.f; oA.y = 0.f;
        v2f oB = oA;
        v2f tp;
        tp.x = lA0;  tp.y = A0.x;  oA = __builtin_elementwise_fma(wgp[0], tp, oA);
                                    oA = __builtin_elementwise_fma(wgp[1], A0, oA);
        tp.x = A0.y; tp.y = rA0;   oA = __builtin_elementwise_fma(wgp[2], tp, oA);
        tp.x = lA1;  tp.y = A1.x;  oA = __builtin_elementwise_fma(wgp[3], tp, oA);
                                    oA = __builtin_elementwise_fma(wgp[4], A1, oA);
        tp.x = A1.y; tp.y = rA1;   oA = __builtin_elementwise_fma(wgp[5], tp, oA);
        tp.x = lA2;  tp.y = A2.x;  oA = __builtin_elementwise_fma(wgp[6], tp, oA);
                                    oA = __builtin_elementwise_fma(wgp[7], A2, oA);
        tp.x = A2.y; tp.y = rA2;   oA = __builtin_elementwise_fma(wgp[8], tp, oA);

        tp.x = lE0;  tp.y = E0.x;  oB = __builtin_elementwise_fma(wgp[0], tp, oB);
                                    oB = __builtin_elementwise_fma(wgp[1], E0, oB);
        tp.x = E0.y; tp.y = rE0;   oB = __builtin_elementwise_fma(wgp[2], tp, oB);
        tp.x = lE1;  tp.y = E1.x;  oB = __builtin_elementwise_fma(wgp[3], tp, oB);
                                    oB = __builtin_elementwise_fma(wgp[4], E1, oB);
        tp.x = E1.y; tp.y = rE1;   oB = __builtin_elementwise_fma(wgp[5], tp, oB);
        tp.x = lE2;  tp.y = E2.x;  oB = __builtin_elementwise_fma(wgp[6], tp, oB);
                                    oB = __builtin_elementwise_fma(wgp[7], E2, oB);
        tp.x = E2.y; tp.y = rE2;   oB = __builtin_elementwise_fma(wgp[8], tp, oB);

        __builtin_nontemporal_store(oA, (v2f*)(obc + (size_t)(2 * g)     * PLANE_B + pb0));
        __builtin_nontemporal_store(oB, (v2f*)(obc + (size_t)(2 * g + 1) * PLANE_B + pb0));
    }
}

extern "C" void kernel_launch(void* const* d_in, const int* in_sizes, int n_in,
                              void* d_out, int out_size, void* d_ws, size_t ws_size,
                              hipStream_t stream)
{
    const float* x  = (const float*)d_in[0];
    const float* w1 = (const float*)d_in[1];
    const float* b1 = (const float*)d_in[2];
    const float* pa = (const float*)d_in[3];
    const float* w2 = (const float*)d_in[4];
    const float* b2 = (const float*)d_in[5];
    float* out = (float*)d_out;

    hipLaunchKernelGGL(invol_fused, dim3(1024), dim3(256), 0, stream,
                       x, w1, b1, pa, w2, b2, out);
}